// Round 4
// baseline (7370.657 us; speedup 1.0000x reference)
//
#include <hip/hip_runtime.h>
#include <hip/hip_bf16.h>

#define BB 64
#define VV 2048
#define ENCD 128
#define TT 100
#define EMBD 256
#define DECD 512
#define ATTD 256
#define NVOCAB 29

typedef unsigned int u32;
typedef unsigned short u16;

__device__ __forceinline__ float sigf(float x) { return 1.0f / (1.0f + __expf(-x)); }
__device__ __forceinline__ u16 to_bf16(float f) {
    u32 u = __float_as_uint(f);
    u += 0x7fffu + ((u >> 16) & 1u);       // round-to-nearest-even
    return (u16)(u >> 16);
}

// ---------------- one-time init kernels ----------------

__global__ __launch_bounds__(256) void k_transpose(const float* __restrict__ W_dec,
                                                   const float* __restrict__ W_beta,
                                                   float* __restrict__ W_decT,
                                                   float* __restrict__ W_betaT) {
    int i = blockIdx.x * 256 + threadIdx.x;
    if (i < DECD * ATTD) {
        int l = i / ATTD, a = i % ATTD;
        W_decT[i] = W_dec[a * DECD + l];
    }
    int j = i - DECD * ATTD;
    if (j >= 0 && j < DECD * ENCD) {
        int l = j / ENCD, e = j % ENCD;
        W_betaT[j] = W_beta[e * DECD + l];
    }
}

// enc_attT[b][a][v] = bf16( enc[b][v][:] . W_enc[a][:] + b_enc[a] )  (8 acc/thread)
// Also emits enc_bf (bf16 copy of encoder) for the awe stage.
__global__ __launch_bounds__(256) void k_enc_att(const float* __restrict__ enc,
                                                 const float* __restrict__ W_enc,
                                                 const float* __restrict__ b_enc,
                                                 u16* __restrict__ enc_attT,
                                                 u16* __restrict__ enc_bf) {
    __shared__ float tile[64][ENCD + 1];   // +1 pad: conflict-free column reads
    int b = blockIdx.y, v0 = blockIdx.x * 64;
    int t = threadIdx.x;
    const float* src = enc + ((size_t)b * VV + v0) * ENCD;
    u16* dstb = enc_bf + ((size_t)b * VV + v0) * ENCD;
    for (int i = t; i < 64 * ENCD; i += 256) {
        float x = src[i];
        tile[i >> 7][i & 127] = x;
        dstb[i] = to_bf16(x);
    }
    __syncthreads();
    int vl = t & 63;
    int ag = __builtin_amdgcn_readfirstlane(t >> 6);   // wave-uniform -> scalar weight loads
    for (int ao = 0; ao < 8; ao++) {
        int a0 = ag * 64 + ao * 8;
        float acc[8];
        #pragma unroll
        for (int j = 0; j < 8; j++) acc[j] = b_enc[a0 + j];
        const float* w = W_enc + (size_t)a0 * ENCD;
        for (int k = 0; k < ENCD; k++) {
            float x = tile[vl][k];
            #pragma unroll
            for (int j = 0; j < 8; j++) acc[j] = fmaf(x, w[j * ENCD + k], acc[j]);
        }
        #pragma unroll
        for (int j = 0; j < 8; j++)
            enc_attT[((size_t)b * ATTD + a0 + j) * VV + v0 + vl] = to_bf16(acc[j]);
    }
}

// mean_enc -> h0,c0 -> dec_att0, gate0, xT(emb0 + h0 rows), lengths output
__global__ __launch_bounds__(512) void k_init(const float* __restrict__ enc,
                                              const int* __restrict__ lens,
                                              const int* __restrict__ captions,
                                              const float* __restrict__ emb_W,
                                              const float* __restrict__ W_init_h,
                                              const float* __restrict__ b_init_h,
                                              const float* __restrict__ W_init_c,
                                              const float* __restrict__ b_init_c,
                                              const float* __restrict__ W_decT,
                                              const float* __restrict__ b_dec,
                                              const float* __restrict__ W_betaT,
                                              const float* __restrict__ b_beta,
                                              float* __restrict__ c0,
                                              float* __restrict__ xT,
                                              float* __restrict__ dec_att,
                                              float* __restrict__ gate,
                                              float* __restrict__ out_len) {
    __shared__ float part[512];
    __shared__ float mean[ENCD];
    __shared__ float h_s[DECD];
    int b = blockIdx.x, t = threadIdx.x;
    int e = t & 127, ch = t >> 7;
    float s = 0.f;
    const float* rowb = enc + (size_t)b * VV * ENCD;
    for (int v = ch * 512; v < ch * 512 + 512; v++) s += rowb[(size_t)v * ENCD + e];
    part[t] = s;
    __syncthreads();
    if (ch == 0) mean[e] = (part[e] + part[128 + e] + part[256 + e] + part[384 + e]) * (1.0f / VV);
    __syncthreads();
    {
        int d = t;
        float hh = b_init_h[d], cc = b_init_c[d];
        for (int k = 0; k < ENCD; k++) {
            hh = fmaf(mean[k], W_init_h[d * ENCD + k], hh);
            cc = fmaf(mean[k], W_init_c[d * ENCD + k], cc);
        }
        c0[b * DECD + d] = cc;
        h_s[d] = hh;
        xT[(384 + d) * BB + b] = hh;       // h part of unified x
    }
    __syncthreads();
    if (t < ATTD) {
        float s2 = b_dec[t];
        for (int l = 0; l < DECD; l++) s2 = fmaf(h_s[l], W_decT[l * ATTD + t], s2);
        dec_att[b * ATTD + t] = s2;
    } else if (t < ATTD + ENCD) {
        int ee = t - ATTD;
        float s2 = b_beta[ee];
        for (int l = 0; l < DECD; l++) s2 = fmaf(h_s[l], W_betaT[l * ENCD + ee], s2);
        gate[b * ENCD + ee] = sigf(s2);
    } else {
        int k = t - 384;
        int cap = captions[b * TT + 0];
        xT[k * BB + b] = emb_W[cap * EMBD + k];
        xT[(k + 128) * BB + b] = emb_W[cap * EMBD + k + 128];
    }
    if (t == 0) out_len[b] = (float)lens[b];
}

// ---------------- per-step kernels (3 per step) ----------------

// Fused: blocks 0..511   = scores -> exp -> denom + UNNORMALIZED awe partials
//        blocks 512..895 = LSTM gate partial GEMM for kc in {0,1,3,4,5,6}
//                          (independent of this step's attention: only needs xT)
__global__ __launch_bounds__(256) void k_att(const u16* __restrict__ enc_attT,
                                             const u16* __restrict__ enc_bf,
                                             const float* __restrict__ dec_att,
                                             const float* __restrict__ w_full,
                                             const int* __restrict__ lens,
                                             const float* __restrict__ xT,
                                             const float* __restrict__ W_ih,
                                             const float* __restrict__ W_hh,
                                             const float* __restrict__ b_ih,
                                             const float* __restrict__ b_hh,
                                             float* __restrict__ escore,
                                             float* __restrict__ denom,
                                             float* __restrict__ awe,
                                             float* __restrict__ gates_part, int ts) {
    int blk = blockIdx.x, t = threadIdx.x;
    if (blk < 512) {
        int b = blk >> 3, v0 = (blk & 7) << 8;
        if (ts >= lens[b]) return;         // lengths sorted desc; uniform per block
        __shared__ float esh[256];
        __shared__ float dred[4];
        __shared__ float red[4][ENCD];
        int v = v0 + t;
        const u16* sp = enc_attT + (size_t)b * ATTD * VV + v;
        const float* db = dec_att + b * ATTD;   // uniform addr -> s_load
        float s = 0.f;
        #pragma unroll 16
        for (int a = 0; a < ATTD; a++) {
            float x = __uint_as_float((u32)sp[(size_t)a * VV] << 16);
            s = fmaf(fmaxf(x + db[a], 0.f), w_full[a], s);   // b_full dropped
        }
        float e = __expf(s);               // |s| < ~3, no max-subtraction needed
        escore[b * VV + v] = e;
        esh[t] = e;
        float ss = e;
        for (int o = 32; o > 0; o >>= 1) ss += __shfl_down(ss, o);
        if ((t & 63) == 0) dred[t >> 6] = ss;
        __syncthreads();
        if (t == 0) atomicAdd(denom + ts * BB + b, dred[0] + dred[1] + dred[2] + dred[3]);
        // awe partial from bf16 encoder, e-pairs packed in u32
        int ep = t & 63, wv = t >> 6;
        const u32* eb = (const u32*)(enc_bf + ((size_t)b * VV + v0) * ENCD) + ep;
        float a0 = 0.f, a1 = 0.f;
        #pragma unroll 8
        for (int vv = wv; vv < 256; vv += 4) {
            u32 u = eb[(size_t)vv * 64];
            float sc = esh[vv];            // wave-uniform -> broadcast
            a0 = fmaf(__uint_as_float(u << 16), sc, a0);
            a1 = fmaf(__uint_as_float(u & 0xffff0000u), sc, a1);
        }
        red[wv][2 * ep] = a0;
        red[wv][2 * ep + 1] = a1;
        __syncthreads();
        if (t < ENCD)
            atomicAdd(awe + ((size_t)ts * BB + b) * ENCD + t,
                      red[0][t] + red[1][t] + red[2][t] + red[3][t]);
    } else {
        int idx = blk - 512;
        int kcp = idx >> 6;
        int kc = kcp < 2 ? kcp : kcp + 1;  // {0,1,3,4,5,6}
        int gt = idx & 63;
        int lane = t & 63, wv = t >> 6;
        int gbase = gt * 32 + wv * 8;
        int gb = __builtin_amdgcn_readfirstlane(gbase);
        int k0 = kc * 128;
        float acc[8];
        #pragma unroll
        for (int j = 0; j < 8; j++)
            acc[j] = (kc == 0) ? (b_ih[gb + j] + b_hh[gb + j]) : 0.f;
        if (kc < 2) {                       // emb columns 0..255
            for (int kk = 0; kk < 128; kk++) {
                float xv = xT[(k0 + kk) * BB + lane];
                #pragma unroll
                for (int j = 0; j < 8; j++)
                    acc[j] = fmaf(xv, W_ih[(gb + j) * 384 + k0 + kk], acc[j]);
            }
        } else {                            // h columns (W_hh cols 0..511)
            const float* Wh = W_hh + (k0 - 384);
            for (int kk = 0; kk < 128; kk++) {
                float xv = xT[(k0 + kk) * BB + lane];
                #pragma unroll
                for (int j = 0; j < 8; j++)
                    acc[j] = fmaf(xv, Wh[(gb + j) * DECD + kk], acc[j]);
            }
        }
        float4* o4 = (float4*)(gates_part + ((size_t)kc * BB + lane) * 2048 + gbase);
        o4[0] = make_float4(acc[0], acc[1], acc[2], acc[3]);
        o4[1] = make_float4(acc[4], acc[5], acc[6], acc[7]);
    }
}

// blocks 0..63  : kc==2 GEMM (gated awe columns; awe normalized here via 1/denom)
// blocks 64..127: alphas = escore/denom
__global__ __launch_bounds__(256) void k_mid(const float* __restrict__ escore,
                                             const float* __restrict__ denom,
                                             const int* __restrict__ lens,
                                             const float* __restrict__ awe,
                                             const float* __restrict__ gate,
                                             const float* __restrict__ W_ih,
                                             float* __restrict__ gates_part,
                                             float* __restrict__ alphas, int ts) {
    int blk = blockIdx.x, t = threadIdx.x;
    if (blk < 64) {
        __shared__ float gawe[BB][ENCD + 1];
        __shared__ float inv_s[BB];
        if (t < BB) {
            float dn = denom[ts * BB + t];
            inv_s[t] = dn > 0.f ? 1.f / dn : 0.f;   // inactive b: partials unused by k_cell
        }
        __syncthreads();
        for (int i = t; i < BB * ENCD; i += 256) {
            int bb = i >> 7, ee = i & 127;
            gawe[bb][ee] = gate[bb * ENCD + ee] *
                           awe[((size_t)ts * BB + bb) * ENCD + ee] * inv_s[bb];
        }
        __syncthreads();
        int lane = t & 63, wv = t >> 6;
        int gbase = blk * 32 + wv * 8;
        int gb = __builtin_amdgcn_readfirstlane(gbase);
        float acc[8] = {0.f, 0.f, 0.f, 0.f, 0.f, 0.f, 0.f, 0.f};
        for (int kk = 0; kk < ENCD; kk++) {
            float xv = gawe[lane][kk];
            #pragma unroll
            for (int j = 0; j < 8; j++)
                acc[j] = fmaf(xv, W_ih[(gb + j) * 384 + 256 + kk], acc[j]);
        }
        float4* o4 = (float4*)(gates_part + ((size_t)2 * BB + lane) * 2048 + gbase);
        o4[0] = make_float4(acc[0], acc[1], acc[2], acc[3]);
        o4[1] = make_float4(acc[4], acc[5], acc[6], acc[7]);
    } else {
        int b = blk - 64;
        if (ts < lens[b]) {
            float inv = 1.f / denom[ts * BB + b];
            size_t obase = ((size_t)b * TT + ts) * VV;
            const float* es = escore + b * VV;
            for (int i = t; i < VV; i += 256) alphas[obase + i] = es[i] * inv;
        }
    }
}

// 4 parts per b (256 blocks): each recomputes the cheap gates reduction, then
// part0: cell write + xT(h) + emb(ts+1); part1: dec_att; part2: gate; part3: preds.
__global__ __launch_bounds__(512) void k_cell(const float* __restrict__ gates_part,
                                              const int* __restrict__ lens,
                                              const int* __restrict__ captions,
                                              const float* __restrict__ emb_W,
                                              const float* __restrict__ W_final,
                                              const float* __restrict__ b_final,
                                              const float* __restrict__ W_decT,
                                              const float* __restrict__ b_dec,
                                              const float* __restrict__ W_betaT,
                                              const float* __restrict__ b_beta,
                                              float* __restrict__ c0,
                                              float* __restrict__ c1,
                                              float* __restrict__ xT,
                                              float* __restrict__ dec_att,
                                              float* __restrict__ gate,
                                              float* __restrict__ preds, int ts) {
    int b = blockIdx.x >> 2, part = blockIdx.x & 3;
    if (ts >= lens[b]) return;             // stale state = correct for masked rows
    __shared__ float h_s[DECD];
    __shared__ float red[512];
    int t = threadIdx.x;
    const float* cin  = (ts & 1) ? c1 : c0;   // ping-pong: redundant compute, no RAW race
    float*       cout = (ts & 1) ? c0 : c1;
    {
        float gi = 0.f, gf = 0.f, gg = 0.f, go = 0.f;
        #pragma unroll
        for (int kc = 0; kc < 7; kc++) {
            const float* gp = gates_part + ((size_t)kc * BB + b) * 2048;
            gi += gp[t]; gf += gp[512 + t]; gg += gp[1024 + t]; go += gp[1536 + t];
        }
        gi = sigf(gi); gf = sigf(gf); go = sigf(go); gg = tanhf(gg);
        float cn = fmaf(gf, cin[b * DECD + t], gi * gg);
        float hn = go * tanhf(cn);
        h_s[t] = hn;
        if (part == 0) {
            cout[b * DECD + t] = cn;
            xT[(384 + t) * BB + b] = hn;
        }
    }
    __syncthreads();
    if (part == 0) {                        // emb staging for ts+1
        if (ts + 1 < TT && t < 256) {
            int cap = captions[b * TT + ts + 1];
            xT[t * BB + b] = emb_W[cap * EMBD + t];
        }
    } else if (part == 1) {                 // dec_att: 256 a, K split 2 ways
        int a = t & 255, half = t >> 8;
        float s = 0.f;
        const float* wd = W_decT + (size_t)half * 256 * ATTD + a;
        #pragma unroll 4
        for (int l = 0; l < 256; l++) s = fmaf(h_s[half * 256 + l], wd[(size_t)l * ATTD], s);
        red[t] = s;
        __syncthreads();
        if (t < 256) dec_att[b * ATTD + t] = red[t] + red[t + 256] + b_dec[t];
    } else if (part == 2) {                 // gate: 128 e, K split 4 ways
        int e = t & 127, q = t >> 7;
        float s = 0.f;
        const float* wb = W_betaT + (size_t)q * 128 * ENCD + e;
        #pragma unroll 4
        for (int l = 0; l < 128; l++) s = fmaf(h_s[q * 128 + l], wb[(size_t)l * ENCD], s);
        red[t] = s;
        __syncthreads();
        if (t < 128)
            gate[b * ENCD + t] = sigf(red[t] + red[t + 128] + red[t + 256] + red[t + 384]
                                      + b_beta[t]);
    } else {                                // predictions: 8 waves over 29 vocab
        int lane = t & 63, wv = t >> 6;
        for (int j = wv; j < NVOCAB; j += 8) {
            float s = 0.f;
            #pragma unroll
            for (int i = 0; i < 8; i++)
                s = fmaf(h_s[lane + 64 * i], W_final[j * DECD + lane + 64 * i], s);
            for (int o = 32; o > 0; o >>= 1) s += __shfl_down(s, o);
            if (lane == 0) preds[((size_t)b * TT + ts) * NVOCAB + j] = s + b_final[j];
        }
    }
}

extern "C" void kernel_launch(void* const* d_in, const int* in_sizes, int n_in,
                              void* d_out, int out_size, void* d_ws, size_t ws_size,
                              hipStream_t stream) {
    const float* enc      = (const float*)d_in[0];
    const int*   captions = (const int*)d_in[1];
    const int*   lens     = (const int*)d_in[2];
    const float* emb_W    = (const float*)d_in[3];
    const float* W_enc    = (const float*)d_in[4];
    const float* b_enc    = (const float*)d_in[5];
    const float* W_dec    = (const float*)d_in[6];
    const float* b_dec    = (const float*)d_in[7];
    const float* w_full   = (const float*)d_in[8];
    // d_in[9] b_full: unused — softmax is shift-invariant
    const float* W_ih     = (const float*)d_in[10];
    const float* b_ih     = (const float*)d_in[11];
    const float* W_hh     = (const float*)d_in[12];
    const float* b_hh     = (const float*)d_in[13];
    const float* W_init_h = (const float*)d_in[14];
    const float* b_init_h = (const float*)d_in[15];
    const float* W_init_c = (const float*)d_in[16];
    const float* b_init_c = (const float*)d_in[17];
    const float* W_beta   = (const float*)d_in[18];
    const float* b_beta   = (const float*)d_in[19];
    const float* W_final  = (const float*)d_in[20];
    const float* b_final  = (const float*)d_in[21];

    float* preds   = (float*)d_out;                      // [B][T][VOCAB]
    float* alphas  = preds + (size_t)BB * TT * NVOCAB;   // [B][T][V]
    float* out_len = alphas + (size_t)BB * TT * VV;      // [B] (as float)

    char* ws = (char*)d_ws;
    size_t off = 0;
    auto alloc = [&](size_t bytes) {
        char* p = ws + off;
        off += (bytes + 255) & ~(size_t)255;
        return p;
    };
    u16*   enc_attT   = (u16*)  alloc((size_t)BB * ATTD * VV * sizeof(u16));   // 67 MB
    u16*   enc_bf     = (u16*)  alloc((size_t)BB * VV * ENCD * sizeof(u16));   // 33.5 MB
    float* escore     = (float*)alloc((size_t)BB * VV * sizeof(float));
    char*  zbase      = ws + off;                                              // zeroed region
    float* denom      = (float*)alloc((size_t)TT * BB * sizeof(float));
    float* awe        = (float*)alloc((size_t)TT * BB * ENCD * sizeof(float));
    size_t zbytes     = (size_t)((ws + off) - zbase);
    float* dec_att    = (float*)alloc((size_t)BB * ATTD * sizeof(float));
    float* gate       = (float*)alloc((size_t)BB * ENCD * sizeof(float));
    float* xT         = (float*)alloc((size_t)896 * BB * sizeof(float));
    float* gates_part = (float*)alloc((size_t)7 * BB * 2048 * sizeof(float));
    float* c0         = (float*)alloc((size_t)BB * DECD * sizeof(float));
    float* c1         = (float*)alloc((size_t)BB * DECD * sizeof(float));
    float* W_decT     = (float*)alloc((size_t)DECD * ATTD * sizeof(float));
    float* W_betaT    = (float*)alloc((size_t)DECD * ENCD * sizeof(float));

    // masked (b,t) outputs must be exactly 0; atomic targets must start at 0
    hipMemsetAsync(d_out, 0, (size_t)out_size * sizeof(float), stream);
    hipMemsetAsync(zbase, 0, zbytes, stream);

    k_transpose<<<768, 256, 0, stream>>>(W_dec, W_beta, W_decT, W_betaT);
    k_enc_att<<<dim3(VV / 64, BB), 256, 0, stream>>>(enc, W_enc, b_enc, enc_attT, enc_bf);
    k_init<<<BB, 512, 0, stream>>>(enc, lens, captions, emb_W, W_init_h, b_init_h,
                                   W_init_c, b_init_c, W_decT, b_dec, W_betaT, b_beta,
                                   c0, xT, dec_att, gate, out_len);

    for (int t = 0; t < TT; t++) {
        k_att<<<896, 256, 0, stream>>>(enc_attT, enc_bf, dec_att, w_full, lens, xT,
                                       W_ih, W_hh, b_ih, b_hh, escore, denom, awe,
                                       gates_part, t);
        k_mid<<<128, 256, 0, stream>>>(escore, denom, lens, awe, gate, W_ih,
                                       gates_part, alphas, t);
        k_cell<<<256, 512, 0, stream>>>(gates_part, lens, captions, emb_W, W_final, b_final,
                                        W_decT, b_dec, W_betaT, b_beta, c0, c1, xT, dec_att,
                                        gate, preds, t);
    }
}

// Round 5
// 6719.902 us; speedup vs baseline: 1.0968x; 1.0968x over previous
//
#include <hip/hip_runtime.h>
#include <hip/hip_bf16.h>

#define BB 64
#define VV 2048
#define ENCD 128
#define TT 100
#define EMBD 256
#define DECD 512
#define ATTD 256
#define NVOCAB 29

typedef unsigned int u32;
typedef unsigned short u16;

__device__ __forceinline__ float sigf(float x) { return 1.0f / (1.0f + __expf(-x)); }
__device__ __forceinline__ u16 to_bf16(float f) {
    u32 u = __float_as_uint(f);
    u += 0x7fffu + ((u >> 16) & 1u);       // round-to-nearest-even
    return (u16)(u >> 16);
}

// ---------------- one-time init kernels ----------------

// W_decT[DEC][ATT], W_betaT[DEC][ENC], W2T[e][g] = W_ih[g][256+e] (kc2 chunk, coalesced-over-g)
__global__ __launch_bounds__(256) void k_transpose(const float* __restrict__ W_dec,
                                                   const float* __restrict__ W_beta,
                                                   const float* __restrict__ W_ih,
                                                   float* __restrict__ W_decT,
                                                   float* __restrict__ W_betaT,
                                                   float* __restrict__ W2T) {
    int i = blockIdx.x * 256 + threadIdx.x;
    if (i < DECD * ATTD) {
        int l = i / ATTD, a = i % ATTD;
        W_decT[i] = W_dec[a * DECD + l];
    } else if (i < DECD * ATTD + DECD * ENCD) {
        int j = i - DECD * ATTD;
        int l = j / ENCD, e = j % ENCD;
        W_betaT[j] = W_beta[e * DECD + l];
    } else if (i < DECD * ATTD + DECD * ENCD + ENCD * 2048) {
        int j = i - (DECD * ATTD + DECD * ENCD);
        int e = j >> 11, g = j & 2047;
        W2T[j] = W_ih[g * 384 + 256 + e];
    }
}

// enc_attT[b][a][v] = bf16( enc[b][v][:] . W_enc[a][:] + b_enc[a] )  (8 acc/thread)
// Also emits enc_bf (bf16 copy of encoder) for the awe stage.
__global__ __launch_bounds__(256) void k_enc_att(const float* __restrict__ enc,
                                                 const float* __restrict__ W_enc,
                                                 const float* __restrict__ b_enc,
                                                 u16* __restrict__ enc_attT,
                                                 u16* __restrict__ enc_bf) {
    __shared__ float tile[64][ENCD + 1];   // +1 pad: conflict-free column reads
    int b = blockIdx.y, v0 = blockIdx.x * 64;
    int t = threadIdx.x;
    const float* src = enc + ((size_t)b * VV + v0) * ENCD;
    u16* dstb = enc_bf + ((size_t)b * VV + v0) * ENCD;
    for (int i = t; i < 64 * ENCD; i += 256) {
        float x = src[i];
        tile[i >> 7][i & 127] = x;
        dstb[i] = to_bf16(x);
    }
    __syncthreads();
    int vl = t & 63;
    int ag = __builtin_amdgcn_readfirstlane(t >> 6);   // wave-uniform -> scalar weight loads
    for (int ao = 0; ao < 8; ao++) {
        int a0 = ag * 64 + ao * 8;
        float acc[8];
        #pragma unroll
        for (int j = 0; j < 8; j++) acc[j] = b_enc[a0 + j];
        const float* w = W_enc + (size_t)a0 * ENCD;
        for (int k = 0; k < ENCD; k++) {
            float x = tile[vl][k];
            #pragma unroll
            for (int j = 0; j < 8; j++) acc[j] = fmaf(x, w[j * ENCD + k], acc[j]);
        }
        #pragma unroll
        for (int j = 0; j < 8; j++)
            enc_attT[((size_t)b * ATTD + a0 + j) * VV + v0 + vl] = to_bf16(acc[j]);
    }
}

// mean_enc -> h0,c0 -> dec_att0, gate0, xT(emb0 + h0 rows), lengths output
__global__ __launch_bounds__(512) void k_init(const float* __restrict__ enc,
                                              const int* __restrict__ lens,
                                              const int* __restrict__ captions,
                                              const float* __restrict__ emb_W,
                                              const float* __restrict__ W_init_h,
                                              const float* __restrict__ b_init_h,
                                              const float* __restrict__ W_init_c,
                                              const float* __restrict__ b_init_c,
                                              const float* __restrict__ W_decT,
                                              const float* __restrict__ b_dec,
                                              const float* __restrict__ W_betaT,
                                              const float* __restrict__ b_beta,
                                              float* __restrict__ c0,
                                              float* __restrict__ xT,
                                              float* __restrict__ dec_att,
                                              float* __restrict__ gate0,
                                              float* __restrict__ out_len) {
    __shared__ float part[512];
    __shared__ float mean[ENCD];
    __shared__ float h_s[DECD];
    int b = blockIdx.x, t = threadIdx.x;
    int e = t & 127, ch = t >> 7;
    float s = 0.f;
    const float* rowb = enc + (size_t)b * VV * ENCD;
    for (int v = ch * 512; v < ch * 512 + 512; v++) s += rowb[(size_t)v * ENCD + e];
    part[t] = s;
    __syncthreads();
    if (ch == 0) mean[e] = (part[e] + part[128 + e] + part[256 + e] + part[384 + e]) * (1.0f / VV);
    __syncthreads();
    {
        int d = t;
        float hh = b_init_h[d], cc = b_init_c[d];
        for (int k = 0; k < ENCD; k++) {
            hh = fmaf(mean[k], W_init_h[d * ENCD + k], hh);
            cc = fmaf(mean[k], W_init_c[d * ENCD + k], cc);
        }
        c0[b * DECD + d] = cc;
        h_s[d] = hh;
        xT[(384 + d) * BB + b] = hh;       // h part of unified x
    }
    __syncthreads();
    if (t < ATTD) {
        float s2 = b_dec[t];
        for (int l = 0; l < DECD; l++) s2 = fmaf(h_s[l], W_decT[l * ATTD + t], s2);
        dec_att[b * ATTD + t] = s2;
    } else if (t < ATTD + ENCD) {
        int ee = t - ATTD;
        float s2 = b_beta[ee];
        for (int l = 0; l < DECD; l++) s2 = fmaf(h_s[l], W_betaT[l * ENCD + ee], s2);
        gate0[b * ENCD + ee] = sigf(s2);
    } else {
        int k = t - 384;
        int cap = captions[b * TT + 0];
        xT[k * BB + b] = emb_W[cap * EMBD + k];
        xT[(k + 128) * BB + b] = emb_W[cap * EMBD + k + 128];
    }
    if (t == 0) out_len[b] = (float)lens[b];
}

// ---------------- per-step kernels (2 per step) ----------------

// blocks 0..255  : scores -> exp -> escore; denom slot dpart[b][q]; awe slot pawe[b][q][:]
//                  (2 voxels/thread, packed bf16x2 loads; NO atomics)
// blocks 256..639: LSTM gate partial GEMM for kc in {0,1,3,4,5,6} (needs only prev-step xT)
__global__ __launch_bounds__(256) void k_att(const u16* __restrict__ enc_attT,
                                             const u16* __restrict__ enc_bf,
                                             const float* __restrict__ dec_att,
                                             const float* __restrict__ w_full,
                                             const int* __restrict__ lens,
                                             const float* __restrict__ xT,
                                             const float* __restrict__ W_ih,
                                             const float* __restrict__ W_hh,
                                             const float* __restrict__ b_ih,
                                             const float* __restrict__ b_hh,
                                             float* __restrict__ escore,
                                             float* __restrict__ dpart,
                                             float* __restrict__ pawe,
                                             float* __restrict__ gates_part, int ts) {
    int blk = blockIdx.x, t = threadIdx.x;
    if (blk < 256) {
        int b = blk >> 2, q = blk & 3, v0 = q << 9;   // 512 voxels per block
        if (ts >= lens[b]) return;         // lengths sorted desc; uniform per block
        __shared__ float esh[512];
        __shared__ float dred[4];
        __shared__ float red[4][ENCD];
        const u32* sp = (const u32*)enc_attT + ((size_t)b * ATTD * VV + v0) / 2 + t;
        const float* db = dec_att + b * ATTD;   // uniform addr -> s_load
        float s0 = 0.f, s1 = 0.f;
        #pragma unroll 16
        for (int a = 0; a < ATTD; a++) {
            u32 u = sp[(size_t)a * (VV / 2)];
            float da = db[a], wf = w_full[a];   // b_full dropped (softmax shift-invariant)
            float x0 = __uint_as_float(u << 16) + da;
            float x1 = __uint_as_float(u & 0xffff0000u) + da;
            s0 = fmaf(fmaxf(x0, 0.f), wf, s0);
            s1 = fmaf(fmaxf(x1, 0.f), wf, s1);
        }
        float e0 = __expf(s0), e1 = __expf(s1); // |s| < ~3, no max-subtraction needed
        ((float2*)escore)[((size_t)b * VV + v0) / 2 + t] = make_float2(e0, e1);
        esh[2 * t] = e0;
        esh[2 * t + 1] = e1;
        int lane = t & 63, wv = t >> 6;
        float ss = e0 + e1;
        for (int o = 32; o > 0; o >>= 1) ss += __shfl_down(ss, o);
        if (lane == 0) dred[wv] = ss;
        __syncthreads();
        if (t == 0) dpart[b * 4 + q] = dred[0] + dred[1] + dred[2] + dred[3];
        // awe partial from bf16 encoder, e-pairs packed in u32
        int ep = lane;
        const u32* eb = (const u32*)enc_bf + ((size_t)b * VV + v0) * ENCD / 2 + ep;
        float a0 = 0.f, a1 = 0.f;
        #pragma unroll 8
        for (int vv = wv; vv < 512; vv += 4) {
            u32 u = eb[(size_t)vv * 64];
            float sc = esh[vv];            // wave-uniform -> broadcast
            a0 = fmaf(__uint_as_float(u << 16), sc, a0);
            a1 = fmaf(__uint_as_float(u & 0xffff0000u), sc, a1);
        }
        red[wv][2 * ep] = a0;
        red[wv][2 * ep + 1] = a1;
        __syncthreads();
        if (t < ENCD)
            pawe[((size_t)b * 4 + q) * ENCD + t] =
                red[0][t] + red[1][t] + red[2][t] + red[3][t];
    } else {
        int idx = blk - 256;
        int kcp = idx >> 6;                // slot 0..5
        int kc = kcp < 2 ? kcp : kcp + 1;  // K chunk {0,1,3,4,5,6}
        int gt = idx & 63;
        int lane = t & 63, wv = t >> 6;
        int gbase = gt * 32 + wv * 8;
        int gb = __builtin_amdgcn_readfirstlane(gbase);
        int k0 = kc * 128;
        float acc[8];
        #pragma unroll
        for (int j = 0; j < 8; j++)
            acc[j] = (kc == 0) ? (b_ih[gb + j] + b_hh[gb + j]) : 0.f;
        if (kc < 2) {                       // emb columns 0..255
            for (int kk = 0; kk < 128; kk++) {
                float xv = xT[(k0 + kk) * BB + lane];
                #pragma unroll
                for (int j = 0; j < 8; j++)
                    acc[j] = fmaf(xv, W_ih[(gb + j) * 384 + k0 + kk], acc[j]);
            }
        } else {                            // h columns (W_hh cols 0..511)
            const float* Wh = W_hh + (k0 - 384);
            for (int kk = 0; kk < 128; kk++) {
                float xv = xT[(k0 + kk) * BB + lane];
                #pragma unroll
                for (int j = 0; j < 8; j++)
                    acc[j] = fmaf(xv, Wh[(gb + j) * DECD + kk], acc[j]);
            }
        }
        float4* o4 = (float4*)(gates_part + ((size_t)kcp * BB + lane) * 2048 + gbase);
        o4[0] = make_float4(acc[0], acc[1], acc[2], acc[3]);
        o4[1] = make_float4(acc[4], acc[5], acc[6], acc[7]);
    }
}

// 2 parts per b (128 blocks x 512): both sum denom slots -> inv, build gawe, add the
// kc2 contribution in-block (W2T coalesced), cell update. Then:
// part0: cout + xT(h) + dec_att + emb(ts+1); part1: alphas + gate_next + preds.
__global__ __launch_bounds__(512) void k_cell(const float* __restrict__ gates_part,
                                              const float* __restrict__ dpart,
                                              const float* __restrict__ pawe,
                                              const int* __restrict__ lens,
                                              const int* __restrict__ captions,
                                              const float* __restrict__ emb_W,
                                              const float* __restrict__ W2T,
                                              const float* __restrict__ W_final,
                                              const float* __restrict__ b_final,
                                              const float* __restrict__ W_decT,
                                              const float* __restrict__ b_dec,
                                              const float* __restrict__ W_betaT,
                                              const float* __restrict__ b_beta,
                                              const float* __restrict__ escore,
                                              float* __restrict__ gate0,
                                              float* __restrict__ gate1,
                                              float* __restrict__ c0,
                                              float* __restrict__ c1,
                                              float* __restrict__ xT,
                                              float* __restrict__ dec_att,
                                              float* __restrict__ preds,
                                              float* __restrict__ alphas, int ts) {
    int b = blockIdx.x >> 1, part = blockIdx.x & 1;
    if (ts >= lens[b]) return;             // stale state = correct for masked rows
    __shared__ float gawe_s[ENCD];
    __shared__ float h_s[DECD];
    __shared__ float red[512];
    int t = threadIdx.x;
    const float* dp = dpart + b * 4;       // uniform -> s_loads, per-thread redundant
    float inv = 1.0f / (dp[0] + dp[1] + dp[2] + dp[3]);
    const float* gprev = (ts & 1) ? gate1 : gate0;   // ping-pong: read-prev/write-next
    float*       gnext = (ts & 1) ? gate0 : gate1;
    if (t < ENCD) {
        const float* pw = pawe + (size_t)b * 4 * ENCD + t;
        float aw = (pw[0] + pw[ENCD] + pw[2 * ENCD] + pw[3 * ENCD]) * inv;
        gawe_s[t] = gprev[b * ENCD + t] * aw;
    }
    __syncthreads();
    const float* cin  = (ts & 1) ? c1 : c0;
    float*       cout = (ts & 1) ? c0 : c1;
    {
        float gi = 0.f, gf = 0.f, gg = 0.f, go = 0.f;
        #pragma unroll
        for (int sc = 0; sc < 6; sc++) {
            const float* gp = gates_part + ((size_t)sc * BB + b) * 2048;
            gi += gp[t]; gf += gp[512 + t]; gg += gp[1024 + t]; go += gp[1536 + t];
        }
        #pragma unroll 4
        for (int e = 0; e < ENCD; e++) {   // kc2: coalesced W2T rows, gawe broadcast
            const float* w = W2T + (size_t)e * 2048;
            float ge = gawe_s[e];
            gi = fmaf(w[t], ge, gi);
            gf = fmaf(w[512 + t], ge, gf);
            gg = fmaf(w[1024 + t], ge, gg);
            go = fmaf(w[1536 + t], ge, go);
        }
        gi = sigf(gi); gf = sigf(gf); go = sigf(go); gg = tanhf(gg);
        float cn = fmaf(gf, cin[b * DECD + t], gi * gg);
        float hn = go * tanhf(cn);
        h_s[t] = hn;
        if (part == 0) {
            cout[b * DECD + t] = cn;
            xT[(384 + t) * BB + b] = hn;
        }
    }
    __syncthreads();
    if (part == 0) {
        int a = t & 255, half = t >> 8;    // dec_att: 256 a, K split 2 ways
        float s = 0.f;
        const float* wd = W_decT + (size_t)half * 256 * ATTD + a;
        #pragma unroll 4
        for (int l = 0; l < 256; l++) s = fmaf(h_s[half * 256 + l], wd[(size_t)l * ATTD], s);
        red[t] = s;
        __syncthreads();
        if (t < 256) {
            dec_att[b * ATTD + t] = red[t] + red[t + 256] + b_dec[t];
        } else if (ts + 1 < TT) {          // emb staging for ts+1 (threads 256..511)
            int k = t - 256;
            int cap = captions[b * TT + ts + 1];
            xT[k * BB + b] = emb_W[cap * EMBD + k];
        }
    } else {
        float* al = alphas + ((size_t)b * TT + ts) * VV;
        const float* es = escore + b * VV;
        #pragma unroll
        for (int i = t; i < VV; i += 512) al[i] = es[i] * inv;
        int e = t & 127, qq = t >> 7;      // gate: 128 e, K split 4 ways
        float s = 0.f;
        const float* wb = W_betaT + (size_t)qq * 128 * ENCD + e;
        #pragma unroll 4
        for (int l = 0; l < 128; l++) s = fmaf(h_s[qq * 128 + l], wb[(size_t)l * ENCD], s);
        red[t] = s;
        __syncthreads();
        if (t < 128)
            gnext[b * ENCD + t] = sigf(red[t] + red[t + 128] + red[t + 256] + red[t + 384]
                                       + b_beta[t]);
        int lane = t & 63, wv = t >> 6;    // predictions: 8 waves over 29 vocab
        for (int j = wv; j < NVOCAB; j += 8) {
            float s2 = 0.f;
            #pragma unroll
            for (int i = 0; i < 8; i++)
                s2 = fmaf(h_s[lane + 64 * i], W_final[j * DECD + lane + 64 * i], s2);
            for (int o = 32; o > 0; o >>= 1) s2 += __shfl_down(s2, o);
            if (lane == 0) preds[((size_t)b * TT + ts) * NVOCAB + j] = s2 + b_final[j];
        }
    }
}

extern "C" void kernel_launch(void* const* d_in, const int* in_sizes, int n_in,
                              void* d_out, int out_size, void* d_ws, size_t ws_size,
                              hipStream_t stream) {
    const float* enc      = (const float*)d_in[0];
    const int*   captions = (const int*)d_in[1];
    const int*   lens     = (const int*)d_in[2];
    const float* emb_W    = (const float*)d_in[3];
    const float* W_enc    = (const float*)d_in[4];
    const float* b_enc    = (const float*)d_in[5];
    const float* W_dec    = (const float*)d_in[6];
    const float* b_dec    = (const float*)d_in[7];
    const float* w_full   = (const float*)d_in[8];
    // d_in[9] b_full: unused — softmax is shift-invariant
    const float* W_ih     = (const float*)d_in[10];
    const float* b_ih     = (const float*)d_in[11];
    const float* W_hh     = (const float*)d_in[12];
    const float* b_hh     = (const float*)d_in[13];
    const float* W_init_h = (const float*)d_in[14];
    const float* b_init_h = (const float*)d_in[15];
    const float* W_init_c = (const float*)d_in[16];
    const float* b_init_c = (const float*)d_in[17];
    const float* W_beta   = (const float*)d_in[18];
    const float* b_beta   = (const float*)d_in[19];
    const float* W_final  = (const float*)d_in[20];
    const float* b_final  = (const float*)d_in[21];

    float* preds   = (float*)d_out;                      // [B][T][VOCAB]
    float* alphas  = preds + (size_t)BB * TT * NVOCAB;   // [B][T][V]
    float* out_len = alphas + (size_t)BB * TT * VV;      // [B] (as float)

    char* ws = (char*)d_ws;
    size_t off = 0;
    auto alloc = [&](size_t bytes) {
        char* p = ws + off;
        off += (bytes + 255) & ~(size_t)255;
        return p;
    };
    u16*   enc_attT   = (u16*)  alloc((size_t)BB * ATTD * VV * sizeof(u16));   // 67 MB
    u16*   enc_bf     = (u16*)  alloc((size_t)BB * VV * ENCD * sizeof(u16));   // 33.5 MB
    float* escore     = (float*)alloc((size_t)BB * VV * sizeof(float));
    float* dpart      = (float*)alloc((size_t)BB * 4 * sizeof(float));
    float* pawe       = (float*)alloc((size_t)BB * 4 * ENCD * sizeof(float));
    float* dec_att    = (float*)alloc((size_t)BB * ATTD * sizeof(float));
    float* gate0      = (float*)alloc((size_t)BB * ENCD * sizeof(float));
    float* gate1      = (float*)alloc((size_t)BB * ENCD * sizeof(float));
    float* xT         = (float*)alloc((size_t)896 * BB * sizeof(float));
    float* gates_part = (float*)alloc((size_t)6 * BB * 2048 * sizeof(float));
    float* c0         = (float*)alloc((size_t)BB * DECD * sizeof(float));
    float* c1         = (float*)alloc((size_t)BB * DECD * sizeof(float));
    float* W_decT     = (float*)alloc((size_t)DECD * ATTD * sizeof(float));
    float* W_betaT    = (float*)alloc((size_t)DECD * ENCD * sizeof(float));
    float* W2T        = (float*)alloc((size_t)ENCD * 2048 * sizeof(float));

    // masked (b,t) outputs must be exactly 0 (slot buffers need no zero-init:
    // they are always written by the same step that reads them)
    hipMemsetAsync(d_out, 0, (size_t)out_size * sizeof(float), stream);

    k_transpose<<<1792, 256, 0, stream>>>(W_dec, W_beta, W_ih, W_decT, W_betaT, W2T);
    k_enc_att<<<dim3(VV / 64, BB), 256, 0, stream>>>(enc, W_enc, b_enc, enc_attT, enc_bf);
    k_init<<<BB, 512, 0, stream>>>(enc, lens, captions, emb_W, W_init_h, b_init_h,
                                   W_init_c, b_init_c, W_decT, b_dec, W_betaT, b_beta,
                                   c0, xT, dec_att, gate0, out_len);

    for (int t = 0; t < TT; t++) {
        k_att<<<640, 256, 0, stream>>>(enc_attT, enc_bf, dec_att, w_full, lens, xT,
                                       W_ih, W_hh, b_ih, b_hh, escore, dpart, pawe,
                                       gates_part, t);
        k_cell<<<128, 512, 0, stream>>>(gates_part, dpart, pawe, lens, captions, emb_W,
                                        W2T, W_final, b_final, W_decT, b_dec, W_betaT,
                                        b_beta, escore, gate0, gate1, c0, c1, xT, dec_att,
                                        preds, alphas, t);
    }
}